// Round 17
// baseline (1658.485 us; speedup 1.0000x reference)
//
#include <hip/hip_runtime.h>
#include <hip/hip_bf16.h>

// MoE experts MLP: E=8, T=2048, H=2048, F=4096, fp32 in/out.
// Pre-pass: X -> bf16 (Xb); W1,W2 -> W1T,W2T [F][H] bf16; W3 -> W3T [H][F] bf16.
// gateup: h = silu(x@W1+b1)*(x@W2+b2) -> bf16 h [T][F] (ws), dual-GEMM 256x128.
// down:   out = (h@W3 + b3) * probs, GEMM 256x256.
// r17 = r16 design + the missing PROLOGUE DRAIN (r16's NaN: first-iteration
// frag reads raced tile0's own staging). B-operand (weights) streamed
// GLOBAL->REGISTERS (L2-served via r13 XCD column pinning); only A staged in
// LDS (3-buffer). One barrier per K-step. Ledger: per window exactly
// {8 b-loads + 2 stage} (gateup) / {4 + 2} (down) issue -> vmcnt(10)/(6)
// guarantees stage(t+1) landed; lgkmcnt(0) before barrier = WAR proof.
// b-loads issued first in each window (longest latency). 16x16x32 MFMA,
// BK=32, B=4 batching.

#define EXPERTS 8
#define TOK 2048
#define HID 2048
#define FFN 4096

#define BKQ 32

typedef float f32x4 __attribute__((ext_vector_type(4)));
typedef __bf16 bf16x8 __attribute__((ext_vector_type(8)));

#if defined(__has_builtin)
#if __has_builtin(__builtin_amdgcn_global_load_lds)
#define HAVE_GLL 1
#endif
#endif

__device__ __forceinline__ void gload_lds16(const __bf16* g, __bf16* l, int lane) {
#ifdef HAVE_GLL
    __builtin_amdgcn_global_load_lds((const __attribute__((address_space(1))) void*)g,
                                     (__attribute__((address_space(3))) void*)l,
                                     16, 0, 0);
#else
    bf16x8 v = *(const bf16x8*)g;
    *(bf16x8*)(l + lane * 8) = v;
#endif
}

// BK=32 rows are 4 octets; swizzle o ^ ((row>>1)&3): conflict-free (measured 0).
__device__ __forceinline__ bf16x8 ldfrag32(const __bf16* s, int row, int fq) {
    return *(const bf16x8*)(s + row * BKQ + ((fq ^ ((row >> 1) & 3)) << 3));
}

// Stage 256x32 bf16 tile (2 gload_lds / thread, 512 threads).
__device__ __forceinline__ void stage256(__bf16* dst, const __bf16* src, size_t ld, int tid) {
    const int w = tid >> 6, l = tid & 63;
    const int ri = l >> 2, o = l & 3;
#pragma unroll
    for (int q = 0; q < 2; ++q) {
        const int row = q * 128 + w * 16 + ri;
        gload_lds16(src + (size_t)row * ld + ((o ^ ((row >> 1) & 3)) << 3),
                    dst + (size_t)(q * 128 + w * 16) * BKQ, l);
    }
}

// -------- transpose + cvt: src fp32 [R][C] -> dst bf16 [C][R], 64x64 tiles ----
__global__ __launch_bounds__(256) void transpose_cvt_kernel(
    const float* __restrict__ src, __bf16* __restrict__ dst,
    int R, int C, size_t srcZ, size_t dstZ)
{
    __shared__ float lds[64 * 68];
    const int t = threadIdx.x;
    const int c0 = blockIdx.x * 64, r0 = blockIdx.y * 64;
    src += (size_t)blockIdx.z * srcZ;
    dst += (size_t)blockIdx.z * dstZ;

    const int rr = t >> 4;
    const int cc = (t & 15) * 4;
#pragma unroll
    for (int p = 0; p < 4; ++p) {
        const int row = p * 16 + rr;
        f32x4 v = *(const f32x4*)(src + (size_t)(r0 + row) * C + c0 + cc);
        *(f32x4*)&lds[row * 68 + (cc ^ (((row >> 3) & 7) << 2))] = v;
    }
    __syncthreads();
    const int o  = t & 7;
    const int c2 = t >> 3;
#pragma unroll
    for (int q = 0; q < 2; ++q) {
        const int c = q * 32 + c2;
        bf16x8 b;
#pragma unroll
        for (int j = 0; j < 8; ++j) {
            b[j] = (__bf16)lds[(8 * o + j) * 68 + (c ^ (o << 2))];
        }
        *(bf16x8*)(dst + (size_t)(c0 + c) * R + r0 + 8 * o) = b;
    }
}

// -------- elementwise fp32 -> bf16 --------
__global__ __launch_bounds__(256) void cvt_kernel(const float* __restrict__ src,
                                                  __bf16* __restrict__ dst, size_t n) {
    const size_t i = ((size_t)blockIdx.x * 256 + threadIdx.x) * 8;
    if (i >= n) return;
    f32x4 v0 = *(const f32x4*)(src + i);
    f32x4 v1 = *(const f32x4*)(src + i + 4);
    bf16x8 b;
#pragma unroll
    for (int k = 0; k < 4; ++k) { b[k] = (__bf16)v0[k]; b[4 + k] = (__bf16)v1[k]; }
    *(bf16x8*)(dst + i) = b;
}

// ---------------- gateup: dual GEMM 256x128, A via LDS, B via L2->regs ------
#define BMU 256
#define BNU 128
#define GXU (FFN / BNU)              // 32
#define ASZ_GU (BMU * BKQ)           // 8192 elems = 16 KiB

__global__ __launch_bounds__(512, 2) void gateup_kernel(
    const __bf16* __restrict__ Xb, const __bf16* __restrict__ wsb,
    const float* __restrict__ b1, const float* __restrict__ b2,
    int e_base, size_t slotElems)
{
    __shared__ __align__(16) __bf16 lds[3 * ASZ_GU];   // 48 KiB (A only)
    const size_t MAT = (size_t)HID * FFN;
    const int tid = threadIdx.x;

    // bijective XCD swizzle (nwg=256); column decomposition: weights L2-pinned.
    int f = blockIdx.y * GXU + blockIdx.x;
    f = (f & 7) * ((GXU * (TOK / BMU)) >> 3) + (f >> 3);
    const int bx = f >> 3;                 // 0..31
    const int by = f & 7;                  // 0..7

    const int e  = e_base + blockIdx.z;
    const int m0 = by * BMU;
    const int n0 = bx * BNU;

    const __bf16* base = wsb + (size_t)blockIdx.z * slotElems;
    const __bf16* gA   = Xb + (size_t)(e * TOK + m0) * HID;
    const __bf16* gB1  = base + (size_t)n0 * HID;             // W1T [F][H]
    const __bf16* gB2  = base + MAT + (size_t)n0 * HID;       // W2T [F][H]

    const int w = tid >> 6, lane = tid & 63;
    const int wm = w >> 1, wn = w & 1;          // 4M x 2N waves, per-wave 64x64
    const int fr = lane & 15, fq = lane >> 4;

    // per-lane B row pointers: row = weight col (n), k contiguous
    const __bf16* pB1 = gB1 + (size_t)(wn * 64 + fr) * HID + fq * 8;
    const __bf16* pB2 = gB2 + (size_t)(wn * 64 + fr) * HID + fq * 8;

    f32x4 accG[4][4] = {};
    f32x4 accU[4][4] = {};

    const int NT = HID / BKQ;  // 64

    // prologue: stage A tiles 0,1 (4 loads); drain tile0 (keep tile1's 2)
    stage256(lds, gA, HID, tid);
    stage256(lds + ASZ_GU, gA + BKQ, HID, tid);
    asm volatile("s_waitcnt vmcnt(2)" ::: "memory");
    __builtin_amdgcn_s_barrier();

    for (int t = 0; t < NT; ++t) {
        const __bf16* bufA = lds + (t % 3) * ASZ_GU;

        // b-frags first (global, L2-served; longest latency), then a (LDS)
        bf16x8 a[4], bg[4], bu[4];
#pragma unroll
        for (int j = 0; j < 4; ++j) {
            bg[j] = *(const bf16x8*)(pB1 + (size_t)j * 16 * HID + t * BKQ);
            bu[j] = *(const bf16x8*)(pB2 + (size_t)j * 16 * HID + t * BKQ);
        }
#pragma unroll
        for (int i = 0; i < 4; ++i) a[i] = ldfrag32(bufA, wm * 64 + i * 16 + fr, fq);
        if (t + 2 < NT)
            stage256(lds + ((t + 2) % 3) * ASZ_GU, gA + (size_t)(t + 2) * BKQ, HID, tid);

        if (t + 1 < NT) {
            asm volatile("s_waitcnt lgkmcnt(0)" ::: "memory");   // WAR: frag reads drained
            if (t + 2 < NT) asm volatile("s_waitcnt vmcnt(10)" ::: "memory");  // 8b+2A window
            else            asm volatile("s_waitcnt vmcnt(8)" ::: "memory");   // 8b window
            __builtin_amdgcn_s_barrier();
        }

        __builtin_amdgcn_s_setprio(1);
#pragma unroll
        for (int j = 0; j < 4; ++j)
#pragma unroll
            for (int i = 0; i < 4; ++i)
                accG[i][j] = __builtin_amdgcn_mfma_f32_16x16x32_bf16(a[i], bg[j], accG[i][j], 0, 0, 0);
#pragma unroll
        for (int j = 0; j < 4; ++j)
#pragma unroll
            for (int i = 0; i < 4; ++i)
                accU[i][j] = __builtin_amdgcn_mfma_f32_16x16x32_bf16(a[i], bu[j], accU[i][j], 0, 0, 0);
        __builtin_amdgcn_s_setprio(0);
    }

    // epilogue: h = silu(gate+b1)*(up+b2) -> bf16 h [T][F] in ws slot
    __bf16* gH = (__bf16*)(base + 3 * MAT) + (size_t)m0 * FFN + n0;
#pragma unroll
    for (int j = 0; j < 4; ++j) {
        const int col = wn * 64 + j * 16 + fr;
        const float bb1 = b1[(size_t)e * FFN + n0 + col];
        const float bb2 = b2[(size_t)e * FFN + n0 + col];
#pragma unroll
        for (int i = 0; i < 4; ++i) {
#pragma unroll
            for (int r = 0; r < 4; ++r) {
                const int row = wm * 64 + i * 16 + fq * 4 + r;
                const float g = accG[i][j][r] + bb1;
                const float u = accU[i][j][r] + bb2;
                const float s = g / (1.0f + __expf(-g));
                gH[(size_t)row * FFN + col] = (__bf16)(s * u);
            }
        }
    }
}

// ---------------- down: GEMM 256x256, A (h) via LDS, B (W3T) via L2->regs ---
#define BMD 256
#define BND 256
#define GXD (HID / BND)              // 8
#define ASZ_D (BMD * BKQ)            // 8192 elems = 16 KiB

__global__ __launch_bounds__(512, 2) void down_kernel(
    const __bf16* __restrict__ wsb, const float* __restrict__ b3,
    const float* __restrict__ probs, float* __restrict__ out,
    int e_base, size_t slotElems)
{
    __shared__ __align__(16) __bf16 lds[3 * ASZ_D];   // 48 KiB (A only)
    const size_t MAT = (size_t)HID * FFN;
    const int tid = threadIdx.x;

    int f = blockIdx.y * GXD + blockIdx.x;
    f = (f & 7) * ((GXD * (TOK / BMD)) >> 3) + (f >> 3);
    const int bx = f >> 3;                 // 0..7
    const int by = f & 7;                  // 0..7

    const int e  = e_base + blockIdx.z;
    const int m0 = by * BMD;
    const int n0 = bx * BND;

    const __bf16* base = wsb + (size_t)blockIdx.z * slotElems;
    const __bf16* gA   = base + 3 * MAT + (size_t)m0 * FFN;   // h [T][F]
    const __bf16* gB   = base + 2 * MAT + (size_t)n0 * FFN;   // W3T [H][F]

    const int w = tid >> 6, lane = tid & 63;
    const int wm = w >> 2, wn = w & 3;          // 2M x 4N waves, per-wave 128x64
    const int fr = lane & 15, fq = lane >> 4;

    const __bf16* pB = gB + (size_t)(wn * 64 + fr) * FFN + fq * 8;

    f32x4 acc[8][4] = {};

    const int NT = FFN / BKQ;  // 128

    // prologue: stage A tiles 0,1 (4 loads); drain tile0 (keep tile1's 2)
    stage256(lds, gA, FFN, tid);
    stage256(lds + ASZ_D, gA + BKQ, FFN, tid);
    asm volatile("s_waitcnt vmcnt(2)" ::: "memory");
    __builtin_amdgcn_s_barrier();

    for (int t = 0; t < NT; ++t) {
        const __bf16* bufA = lds + (t % 3) * ASZ_D;

        bf16x8 a[8], b[4];
#pragma unroll
        for (int j = 0; j < 4; ++j)
            b[j] = *(const bf16x8*)(pB + (size_t)j * 16 * FFN + t * BKQ);
#pragma unroll
        for (int i = 0; i < 8; ++i) a[i] = ldfrag32(bufA, wm * 128 + i * 16 + fr, fq);
        if (t + 2 < NT)
            stage256(lds + ((t + 2) % 3) * ASZ_D, gA + (size_t)(t + 2) * BKQ, FFN, tid);

        if (t + 1 < NT) {
            asm volatile("s_waitcnt lgkmcnt(0)" ::: "memory");
            if (t + 2 < NT) asm volatile("s_waitcnt vmcnt(6)" ::: "memory");   // 4b+2A
            else            asm volatile("s_waitcnt vmcnt(4)" ::: "memory");   // 4b
            __builtin_amdgcn_s_barrier();
        }

        __builtin_amdgcn_s_setprio(1);
#pragma unroll
        for (int j = 0; j < 4; ++j)
#pragma unroll
            for (int i = 0; i < 8; ++i)
                acc[i][j] = __builtin_amdgcn_mfma_f32_16x16x32_bf16(a[i], b[j], acc[i][j], 0, 0, 0);
        __builtin_amdgcn_s_setprio(0);
    }

    float* gO = out + (size_t)(e * TOK + m0) * HID + n0;
    float bb3[4];
#pragma unroll
    for (int j = 0; j < 4; ++j) bb3[j] = b3[(size_t)e * HID + n0 + wn * 64 + j * 16 + fr];
#pragma unroll
    for (int i = 0; i < 8; ++i) {
#pragma unroll
        for (int r = 0; r < 4; ++r) {
            const int row = wm * 128 + i * 16 + fq * 4 + r;
            const float pp = probs[(size_t)e * TOK + m0 + row];
            float* o = gO + (size_t)row * HID;
#pragma unroll
            for (int j = 0; j < 4; ++j) {
                o[wn * 64 + j * 16 + fr] = (acc[i][j][r] + bb3[j]) * pp;
            }
        }
    }
}

extern "C" void kernel_launch(void* const* d_in, const int* in_sizes, int n_in,
                              void* d_out, int out_size, void* d_ws, size_t ws_size,
                              hipStream_t stream) {
    const float* X     = (const float*)d_in[0];
    // d_in[1] tokens_per_expert (int64): equal split, unused
    const float* probs = (const float*)d_in[2];
    const float* W1    = (const float*)d_in[3];
    const float* b1    = (const float*)d_in[4];
    const float* W2    = (const float*)d_in[5];
    const float* b2    = (const float*)d_in[6];
    const float* W3    = (const float*)d_in[7];
    const float* b3    = (const float*)d_in[8];
    float* out = (float*)d_out;

    const size_t MAT = (size_t)HID * FFN;                  // 8,388,608 elems
    const size_t XBE = (size_t)EXPERTS * TOK * HID;        // 33,554,432 elems
    const size_t slotElems = 4 * MAT;                      // W1T,W2T,W3T,h

    int B = 4;
    while (B > 1 && ((size_t)B * slotElems + XBE) * sizeof(__bf16) > ws_size) B >>= 1;

    __bf16* wsb = (__bf16*)d_ws;
    __bf16* Xb  = wsb + (size_t)B * slotElems;

    // X -> bf16 once
    cvt_kernel<<<(int)(XBE / 8 / 256), 256, 0, stream>>>(X, Xb, XBE);

    for (int eb = 0; eb < EXPERTS; eb += B) {
        // W1 [H][F] -> W1T [F][H]; W2 likewise; W3 [F][H] -> W3T [H][F]
        transpose_cvt_kernel<<<dim3(FFN / 64, HID / 64, B), 256, 0, stream>>>(
            W1 + (size_t)eb * MAT, wsb + 0, HID, FFN, MAT, slotElems);
        transpose_cvt_kernel<<<dim3(FFN / 64, HID / 64, B), 256, 0, stream>>>(
            W2 + (size_t)eb * MAT, wsb + MAT, HID, FFN, MAT, slotElems);
        transpose_cvt_kernel<<<dim3(HID / 64, FFN / 64, B), 256, 0, stream>>>(
            W3 + (size_t)eb * MAT, wsb + 2 * MAT, FFN, HID, MAT, slotElems);

        gateup_kernel<<<dim3(GXU, TOK / BMU, B), 512, 0, stream>>>(
            Xb, wsb, b1, b2, eb, slotElems);
        down_kernel<<<dim3(GXD, TOK / BMD, B), 512, 0, stream>>>(
            wsb, b3, probs, out, eb, slotElems);
    }
}

// Round 18
// 999.109 us; speedup vs baseline: 1.6600x; 1.6600x over previous
//
#include <hip/hip_runtime.h>
#include <hip/hip_bf16.h>

// MoE experts MLP: E=8, T=2048, H=2048, F=4096, fp32 in/out.
// Pre-pass: X -> bf16 (Xb); ONE merged kernel transposes+converts W1,W2 ->
// W1T,W2T [F][H] bf16 and W3 -> W3T [H][F] bf16 (blockIdx.y = matrix).
// gateup: h = silu(x@W1+b1)*(x@W2+b2) -> bf16 h [T][F] (ws), dual-GEMM 256x128.
// down:   out = (h@W3 + b3) * probs, GEMM 256x256.
// GEMMs = r13 banked best (1009.6 us), byte-identical: BK=32, 512 thr/8 waves,
// 3-buffer LDS rotation, distance-2 prefetch, counted vmcnt(4) (0 only at
// tail), 2-phase K-step, global_load_lds(16B) pre-swizzled source, setprio,
// B=4, XCD COLUMN grouping (FETCH 541->197 MB), launch_bounds(512,2).
// r18 change: merged transpose launch only (fewer launch gaps, co-filled grid).

#define EXPERTS 8
#define TOK 2048
#define HID 2048
#define FFN 4096

#define BKQ 32

typedef float f32x4 __attribute__((ext_vector_type(4)));
typedef __bf16 bf16x8 __attribute__((ext_vector_type(8)));

#if defined(__has_builtin)
#if __has_builtin(__builtin_amdgcn_global_load_lds)
#define HAVE_GLL 1
#endif
#endif

__device__ __forceinline__ void gload_lds16(const __bf16* g, __bf16* l, int lane) {
#ifdef HAVE_GLL
    __builtin_amdgcn_global_load_lds((const __attribute__((address_space(1))) void*)g,
                                     (__attribute__((address_space(3))) void*)l,
                                     16, 0, 0);
#else
    bf16x8 v = *(const bf16x8*)g;
    *(bf16x8*)(l + lane * 8) = v;
#endif
}

// BK=32 rows are 4 octets; swizzle o ^ ((row>>1)&3): conflict-free (measured 0).
__device__ __forceinline__ bf16x8 ldfrag32(const __bf16* s, int row, int fq) {
    return *(const bf16x8*)(s + row * BKQ + ((fq ^ ((row >> 1) & 3)) << 3));
}

// Stage 256x32 bf16 tile (2 gload_lds / thread, 512 threads).
__device__ __forceinline__ void stage256(__bf16* dst, const __bf16* src, size_t ld, int tid) {
    const int w = tid >> 6, l = tid & 63;
    const int ri = l >> 2, o = l & 3;
#pragma unroll
    for (int q = 0; q < 2; ++q) {
        const int row = q * 128 + w * 16 + ri;
        gload_lds16(src + (size_t)row * ld + ((o ^ ((row >> 1) & 3)) << 3),
                    dst + (size_t)(q * 128 + w * 16) * BKQ, l);
    }
}

// Stage 128x32 bf16 tile (1 gload_lds / thread, 512 threads).
__device__ __forceinline__ void stage128(__bf16* dst, const __bf16* src, size_t ld, int tid) {
    const int w = tid >> 6, l = tid & 63;
    const int ri = l >> 2, o = l & 3;
    const int row = w * 16 + ri;
    gload_lds16(src + (size_t)row * ld + ((o ^ ((row >> 1) & 3)) << 3),
                dst + (size_t)(w * 16) * BKQ, l);
}

// -------- merged transpose+cvt: W1,W2 [H][F] -> [F][H]; W3 [F][H] -> [H][F] --
// blockIdx.y: 0=W1, 1=W2, 2=W3. blockIdx.z = expert within batch.
__global__ __launch_bounds__(256) void transpose_all_kernel(
    const float* __restrict__ W1, const float* __restrict__ W2,
    const float* __restrict__ W3, __bf16* __restrict__ wsb,
    int e_base, size_t slotElems)
{
    __shared__ float lds[64 * 68];
    const size_t MAT = (size_t)HID * FFN;
    const int t = threadIdx.x;
    const int m = blockIdx.y;
    const int e = e_base + blockIdx.z;

    const float* src;
    __bf16* dst;
    int C, csh;   // src is [R][C]; dst is [C][R]
    if (m == 0)      { src = W1 + (size_t)e * MAT; dst = wsb + (size_t)blockIdx.z * slotElems;           C = FFN; csh = 6; }
    else if (m == 1) { src = W2 + (size_t)e * MAT; dst = wsb + (size_t)blockIdx.z * slotElems + MAT;     C = FFN; csh = 6; }
    else             { src = W3 + (size_t)e * MAT; dst = wsb + (size_t)blockIdx.z * slotElems + 2 * MAT; C = HID; csh = 5; }
    const int R = (m == 2) ? FFN : HID;
    const int bx = blockIdx.x & ((1 << csh) - 1);
    const int by = blockIdx.x >> csh;
    const int c0 = bx * 64, r0 = by * 64;

    const int rr = t >> 4;
    const int cc = (t & 15) * 4;
#pragma unroll
    for (int p = 0; p < 4; ++p) {
        const int row = p * 16 + rr;
        f32x4 v = *(const f32x4*)(src + (size_t)(r0 + row) * C + c0 + cc);
        *(f32x4*)&lds[row * 68 + (cc ^ (((row >> 3) & 7) << 2))] = v;
    }
    __syncthreads();
    const int o  = t & 7;
    const int c2 = t >> 3;
#pragma unroll
    for (int q = 0; q < 2; ++q) {
        const int c = q * 32 + c2;
        bf16x8 b;
#pragma unroll
        for (int j = 0; j < 8; ++j) {
            b[j] = (__bf16)lds[(8 * o + j) * 68 + (c ^ (o << 2))];
        }
        *(bf16x8*)(dst + (size_t)(c0 + c) * R + r0 + 8 * o) = b;
    }
}

// -------- elementwise fp32 -> bf16 --------
__global__ __launch_bounds__(256) void cvt_kernel(const float* __restrict__ src,
                                                  __bf16* __restrict__ dst, size_t n) {
    const size_t i = ((size_t)blockIdx.x * 256 + threadIdx.x) * 8;
    if (i >= n) return;
    f32x4 v0 = *(const f32x4*)(src + i);
    f32x4 v1 = *(const f32x4*)(src + i + 4);
    bf16x8 b;
#pragma unroll
    for (int k = 0; k < 4; ++k) { b[k] = (__bf16)v0[k]; b[4 + k] = (__bf16)v1[k]; }
    *(bf16x8*)(dst + i) = b;
}

// ---------------- gateup: dual GEMM 256x128, BK=32, 3-buf pipeline ----------
#define BMU 256
#define BNU 128
#define GXU (FFN / BNU)              // 32
#define ASZ_GU (BMU * BKQ)           // 8192 elems
#define BSZ_GU (BNU * BKQ)           // 4096 elems
#define BUF_GU (ASZ_GU + 2 * BSZ_GU) // 16384 elems = 32 KiB

__global__ __launch_bounds__(512, 2) void gateup_kernel(
    const __bf16* __restrict__ Xb, const __bf16* __restrict__ wsb,
    const float* __restrict__ b1, const float* __restrict__ b2,
    int e_base, size_t slotElems)
{
    __shared__ __align__(16) __bf16 lds[3 * BUF_GU];   // 96 KiB
    const size_t MAT = (size_t)HID * FFN;
    const int tid = threadIdx.x;

    // bijective XCD swizzle (nwg=256); column decomposition: weights L2-pinned.
    int f = blockIdx.y * GXU + blockIdx.x;
    f = (f & 7) * ((GXU * (TOK / BMU)) >> 3) + (f >> 3);
    const int bx = f >> 3;                 // 0..31
    const int by = f & 7;                  // 0..7

    const int e  = e_base + blockIdx.z;
    const int m0 = by * BMU;
    const int n0 = bx * BNU;

    const __bf16* base = wsb + (size_t)blockIdx.z * slotElems;
    const __bf16* gA   = Xb + (size_t)(e * TOK + m0) * HID;
    const __bf16* gB1  = base + (size_t)n0 * HID;
    const __bf16* gB2  = base + MAT + (size_t)n0 * HID;

    const int w = tid >> 6, lane = tid & 63;
    const int wm = w >> 1, wn = w & 1;          // 4M x 2N waves, per-wave 64x64
    const int fr = lane & 15, fq = lane >> 4;

    f32x4 accG[4][4] = {};
    f32x4 accU[4][4] = {};

    const int NT = HID / BKQ;  // 64

    // prologue: stage tiles 0 -> buf0, 1 -> buf1 (8 loads), wait tile0 (keep 4)
#pragma unroll
    for (int t0 = 0; t0 < 2; ++t0) {
        __bf16* d = lds + t0 * BUF_GU;
        const size_t ko = (size_t)t0 * BKQ;
        stage256(d, gA + ko, HID, tid);
        stage128(d + ASZ_GU, gB1 + ko, HID, tid);
        stage128(d + ASZ_GU + BSZ_GU, gB2 + ko, HID, tid);
    }
    asm volatile("s_waitcnt vmcnt(4)" ::: "memory");
    __builtin_amdgcn_s_barrier();

    int cur = 0;
    for (int t = 0; t < NT; ++t) {
        const int nb = (cur == 0) ? 2 : cur - 1;   // (cur+2)%3
        __bf16* d = lds + nb * BUF_GU;
        const size_t ko2 = (size_t)(t + 2) * BKQ;
        const __bf16* bufA  = lds + cur * BUF_GU;
        const __bf16* bufB1 = bufA + ASZ_GU;
        const __bf16* bufB2 = bufB1 + BSZ_GU;

        // ---- phase A: gate ----
        bf16x8 a[4], bg[4];
#pragma unroll
        for (int i = 0; i < 4; ++i) a[i] = ldfrag32(bufA, wm * 64 + i * 16 + fr, fq);
#pragma unroll
        for (int j = 0; j < 4; ++j) bg[j] = ldfrag32(bufB1, wn * 64 + j * 16 + fr, fq);
        if (t + 2 < NT) stage256(d, gA + ko2, HID, tid);           // 2 loads
        asm volatile("" ::: "memory");
        __builtin_amdgcn_s_barrier();
        __builtin_amdgcn_s_setprio(1);
#pragma unroll
        for (int j = 0; j < 4; ++j)
#pragma unroll
            for (int i = 0; i < 4; ++i)
                accG[i][j] = __builtin_amdgcn_mfma_f32_16x16x32_bf16(a[i], bg[j], accG[i][j], 0, 0, 0);
        __builtin_amdgcn_s_setprio(0);

        // ---- phase B: up ----
        bf16x8 bu[4];
#pragma unroll
        for (int j = 0; j < 4; ++j) bu[j] = ldfrag32(bufB2, wn * 64 + j * 16 + fr, fq);
        if (t + 2 < NT) {
            stage128(d + ASZ_GU, gB1 + ko2, HID, tid);             // 1 load
            stage128(d + ASZ_GU + BSZ_GU, gB2 + ko2, HID, tid);    // 1 load
        }
        if (t + 1 < NT) {
            if (t + 2 < NT) asm volatile("s_waitcnt vmcnt(4)" ::: "memory");
            else            asm volatile("s_waitcnt vmcnt(0)" ::: "memory");
        }
        asm volatile("" ::: "memory");
        __builtin_amdgcn_s_barrier();
        __builtin_amdgcn_s_setprio(1);
#pragma unroll
        for (int j = 0; j < 4; ++j)
#pragma unroll
            for (int i = 0; i < 4; ++i)
                accU[i][j] = __builtin_amdgcn_mfma_f32_16x16x32_bf16(a[i], bu[j], accU[i][j], 0, 0, 0);
        __builtin_amdgcn_s_setprio(0);

        cur = (cur == 2) ? 0 : cur + 1;
    }

    // epilogue: h = silu(gate+b1)*(up+b2) -> bf16 h [T][F] in ws slot
    __bf16* gH = (__bf16*)(base + 3 * MAT) + (size_t)m0 * FFN + n0;
#pragma unroll
    for (int j = 0; j < 4; ++j) {
        const int col = wn * 64 + j * 16 + fr;
        const float bb1 = b1[(size_t)e * FFN + n0 + col];
        const float bb2 = b2[(size_t)e * FFN + n0 + col];
#pragma unroll
        for (int i = 0; i < 4; ++i) {
#pragma unroll
            for (int r = 0; r < 4; ++r) {
                const int row = wm * 64 + i * 16 + fq * 4 + r;
                const float g = accG[i][j][r] + bb1;
                const float u = accU[i][j][r] + bb2;
                const float s = g / (1.0f + __expf(-g));
                gH[(size_t)row * FFN + col] = (__bf16)(s * u);
            }
        }
    }
}

// ---------------- down: GEMM 256x256, BK=32, 3-buf pipeline ----------------
#define BMD 256
#define BND 256
#define GXD (HID / BND)              // 8
#define ASZ_D (BMD * BKQ)            // 8192 elems
#define BUF_D (2 * ASZ_D)            // 16384 elems = 32 KiB

__global__ __launch_bounds__(512, 2) void down_kernel(
    const __bf16* __restrict__ wsb, const float* __restrict__ b3,
    const float* __restrict__ probs, float* __restrict__ out,
    int e_base, size_t slotElems)
{
    __shared__ __align__(16) __bf16 lds[3 * BUF_D];
    const size_t MAT = (size_t)HID * FFN;
    const int tid = threadIdx.x;

    // bijective XCD swizzle (nwg=64); column decomposition: W3T L2-pinned.
    int f = blockIdx.y * GXD + blockIdx.x;
    f = (f & 7) * ((GXD * (TOK / BMD)) >> 3) + (f >> 3);
    const int bx = f >> 3;                 // 0..7
    const int by = f & 7;                  // 0..7

    const int e  = e_base + blockIdx.z;
    const int m0 = by * BMD;
    const int n0 = bx * BND;

    const __bf16* base = wsb + (size_t)blockIdx.z * slotElems;
    const __bf16* gA   = base + 3 * MAT + (size_t)m0 * FFN;   // h [T][F]
    const __bf16* gB   = base + 2 * MAT + (size_t)n0 * FFN;   // W3T [H][F]

    const int w = tid >> 6, lane = tid & 63;
    const int wm = w >> 2, wn = w & 3;          // 2M x 4N waves, per-wave 128x64
    const int fr = lane & 15, fq = lane >> 4;

    f32x4 acc[8][4] = {};

    const int NT = FFN / BKQ;  // 128

#pragma unroll
    for (int t0 = 0; t0 < 2; ++t0) {
        __bf16* d = lds + t0 * BUF_D;
        const size_t ko = (size_t)t0 * BKQ;
        stage256(d, gA + ko, FFN, tid);
        stage256(d + ASZ_D, gB + ko, FFN, tid);
    }
    asm volatile("s_waitcnt vmcnt(4)" ::: "memory");
    __builtin_amdgcn_s_barrier();

    int cur = 0;
    for (int t = 0; t < NT; ++t) {
        const int nb = (cur == 0) ? 2 : cur - 1;   // (cur+2)%3
        __bf16* d = lds + nb * BUF_D;
        const size_t ko2 = (size_t)(t + 2) * BKQ;
        const __bf16* bufA = lds + cur * BUF_D;
        const __bf16* bufB = bufA + ASZ_D;

        // ---- phase A: m-half 0 ----
        bf16x8 a0[4], b[4];
#pragma unroll
        for (int i = 0; i < 4; ++i) a0[i] = ldfrag32(bufA, wm * 128 + i * 16 + fr, fq);
#pragma unroll
        for (int j = 0; j < 4; ++j) b[j] = ldfrag32(bufB, wn * 64 + j * 16 + fr, fq);
        if (t + 2 < NT) stage256(d, gA + ko2, FFN, tid);           // 2 loads
        asm volatile("" ::: "memory");
        __builtin_amdgcn_s_barrier();
        __builtin_amdgcn_s_setprio(1);
#pragma unroll
        for (int j = 0; j < 4; ++j)
#pragma unroll
            for (int i = 0; i < 4; ++i)
                acc[i][j] = __builtin_amdgcn_mfma_f32_16x16x32_bf16(a0[i], b[j], acc[i][j], 0, 0, 0);
        __builtin_amdgcn_s_setprio(0);

        // ---- phase B: m-half 1 ----
        bf16x8 a1[4];
#pragma unroll
        for (int i = 0; i < 4; ++i) a1[i] = ldfrag32(bufA, wm * 128 + (i + 4) * 16 + fr, fq);
        if (t + 2 < NT) stage256(d + ASZ_D, gB + ko2, FFN, tid);   // 2 loads
        if (t + 1 < NT) {
            if (t + 2 < NT) asm volatile("s_waitcnt vmcnt(4)" ::: "memory");
            else            asm volatile("s_waitcnt vmcnt(0)" ::: "memory");
        }
        asm volatile("" ::: "memory");
        __builtin_amdgcn_s_barrier();
        __builtin_amdgcn_s_setprio(1);
#pragma unroll
        for (int j = 0; j < 4; ++j)
#pragma unroll
            for (int i = 0; i < 4; ++i)
                acc[i + 4][j] = __builtin_amdgcn_mfma_f32_16x16x32_bf16(a1[i], b[j], acc[i + 4][j], 0, 0, 0);
        __builtin_amdgcn_s_setprio(0);

        cur = (cur == 2) ? 0 : cur + 1;
    }

    float* gO = out + (size_t)(e * TOK + m0) * HID + n0;
    float bb3[4];
#pragma unroll
    for (int j = 0; j < 4; ++j) bb3[j] = b3[(size_t)e * HID + n0 + wn * 64 + j * 16 + fr];
#pragma unroll
    for (int i = 0; i < 8; ++i) {
#pragma unroll
        for (int r = 0; r < 4; ++r) {
            const int row = wm * 128 + i * 16 + fq * 4 + r;
            const float pp = probs[(size_t)e * TOK + m0 + row];
            float* o = gO + (size_t)row * HID;
#pragma unroll
            for (int j = 0; j < 4; ++j) {
                o[wn * 64 + j * 16 + fr] = (acc[i][j][r] + bb3[j]) * pp;
            }
        }
    }
}

extern "C" void kernel_launch(void* const* d_in, const int* in_sizes, int n_in,
                              void* d_out, int out_size, void* d_ws, size_t ws_size,
                              hipStream_t stream) {
    const float* X     = (const float*)d_in[0];
    // d_in[1] tokens_per_expert (int64): equal split, unused
    const float* probs = (const float*)d_in[2];
    const float* W1    = (const float*)d_in[3];
    const float* b1    = (const float*)d_in[4];
    const float* W2    = (const float*)d_in[5];
    const float* b2    = (const float*)d_in[6];
    const float* W3    = (const float*)d_in[7];
    const float* b3    = (const float*)d_in[8];
    float* out = (float*)d_out;

    const size_t MAT = (size_t)HID * FFN;                  // 8,388,608 elems
    const size_t XBE = (size_t)EXPERTS * TOK * HID;        // 33,554,432 elems
    const size_t slotElems = 4 * MAT;                      // W1T,W2T,W3T,h

    int B = 4;
    while (B > 1 && ((size_t)B * slotElems + XBE) * sizeof(__bf16) > ws_size) B >>= 1;

    __bf16* wsb = (__bf16*)d_ws;
    __bf16* Xb  = wsb + (size_t)B * slotElems;

    // X -> bf16 once
    cvt_kernel<<<(int)(XBE / 8 / 256), 256, 0, stream>>>(X, Xb, XBE);

    for (int eb = 0; eb < EXPERTS; eb += B) {
        // one merged launch: W1,W2 [H][F] -> [F][H]; W3 [F][H] -> [H][F]
        transpose_all_kernel<<<dim3(2048, 3, B), 256, 0, stream>>>(
            W1, W2, W3, wsb, eb, slotElems);

        gateup_kernel<<<dim3(GXU, TOK / BMU, B), 512, 0, stream>>>(
            Xb, wsb, b1, b2, eb, slotElems);
        down_kernel<<<dim3(GXD, TOK / BMD, B), 512, 0, stream>>>(
            wsb, b3, probs, out, eb, slotElems);
    }
}